// Round 17
// baseline (187.246 us; speedup 1.0000x reference)
//
#include <hip/hip_runtime.h>

typedef _Float16 f16;
typedef f16 f16x4 __attribute__((ext_vector_type(4)));
typedef f16 f16x8 __attribute__((ext_vector_type(8)));
typedef float f32x4 __attribute__((ext_vector_type(4)));

#define NB 1024
#define NF 64
#define ND 256
#define KWIN 85
#define INDIM 32768
#define OUTC 8192
#define MAXFIX 32
#define FKB 64  // k-chunks per flagged row in fixup pass 1 (512 k each)
// W pre-scaled by 256; lo-parts scaled by 2048; undone in f32 epilogues.
#define WSCALE 256.0f
#define LSCALE 2048.0f
#define INV_WS (1.0f / 256.0f)
#define INV_LS (1.0f / 2048.0f)

__device__ __forceinline__ int swz4(int row, int slot) { return slot ^ ((row ^ (row >> 2)) & 3); }

__device__ __forceinline__ void gl2lds16(const void* g, void* l) {
  __builtin_amdgcn_global_load_lds((const __attribute__((address_space(1))) void*)g,
                                   (__attribute__((address_space(3))) void*)l, 16, 0, 0);
}

// ---------------- merged transpose + fp16 hi/lo-scaled split for W1 and W2 ----------------
// bid < 2048: W1 (32768x256 -> w1T[256][32768]); bid >= 2048: W2 (256x8192 -> w2T[8192][256])
__global__ __launch_bounds__(256) void transpose_split2(const float* __restrict__ W1src,
                                                        f16* __restrict__ w1h, f16* __restrict__ w1l,
                                                        const float* __restrict__ W2src,
                                                        f16* __restrict__ w2h, f16* __restrict__ w2l) {
  __shared__ float tile[64][65];
  int bid = blockIdx.x;
  const float* src;
  f16 *dhi, *dlo;
  int R, C;
  if (bid < 2048) {
    src = W1src; dhi = w1h; dlo = w1l; R = INDIM; C = ND;
  } else {
    bid -= 2048;
    src = W2src; dhi = w2h; dlo = w2l; R = ND; C = OUTC;
  }
  int t = threadIdx.x;
  int tiles_c = C >> 6;
  int tr = bid / tiles_c, tc = bid - tr * tiles_c;
  size_t r0 = (size_t)tr << 6;
  int c0 = tc << 6;
  int rr = t >> 4, cc = (t & 15) << 2;
#pragma unroll
  for (int p = 0; p < 4; ++p) {
    const float4 v = *(const float4*)(src + (r0 + (p << 4) + rr) * C + c0 + cc);
    tile[(p << 4) + rr][cc + 0] = v.x;
    tile[(p << 4) + rr][cc + 1] = v.y;
    tile[(p << 4) + rr][cc + 2] = v.z;
    tile[(p << 4) + rr][cc + 3] = v.w;
  }
  __syncthreads();
  int n = t >> 2, kq = t & 3;
  alignas(16) f16 hv[16];
  alignas(16) f16 lv[16];
#pragma unroll
  for (int e = 0; e < 16; ++e) {
    float x = tile[(kq << 4) + e][n] * WSCALE;
    f16 h = (f16)x;
    hv[e] = h;
    lv[e] = (f16)((x - (float)h) * LSCALE);
  }
  size_t ob = (size_t)(c0 + n) * (size_t)R + r0 + (kq << 4);
  *(f16x8*)(dhi + ob)     = *(const f16x8*)&hv[0];
  *(f16x8*)(dhi + ob + 8) = *(const f16x8*)&hv[8];
  *(f16x8*)(dlo + ob)     = *(const f16x8*)&lv[0];
  *(f16x8*)(dlo + ob + 8) = *(const f16x8*)&lv[8];
}

// ---------------- GEMM1: r14 tile (BM=128 x BN=128, 512 thr, 2 blk/CU) + 2-phase schedule ----------------
__global__ __launch_bounds__(512, 4) void gemm1_kernel(const float* __restrict__ meanp, const float* __restrict__ varp,
                                                       const f16* __restrict__ w1h, const f16* __restrict__ w1l,
                                                       float* __restrict__ partial) {
  __shared__ alignas(16) f16 sAh[2][128 * 32], sAl[2][128 * 32];
  __shared__ alignas(16) f16 sBh[2][128 * 32], sBl[2][128 * 32];
  int t = threadIdx.x;
  int chunk = blockIdx.x & 31;
  int nb = (blockIdx.x >> 5) & 1;
  int rb = blockIdx.x >> 6;
  int bm = rb << 7, bn = nb << 7;
  int wid = t >> 6, lane = t & 63, lr = lane & 15, lk = lane >> 4;
  int wr = wid >> 1, wc = wid & 1;
  f32x4 acc0[2][4] = {};
  f32x4 acc1[2][4] = {};
  int ar = t >> 3, ac4 = t & 7;
  int bnr = t >> 2, bslot = t & 3;

  float4 fly[2];

  auto STAGE_B = [&](int kkv, int buf) {
    int gk = (chunk << 10) + ((kkv & 31) << 5);
    size_t go = (size_t)(bn + bnr) * INDIM + (size_t)gk + (size_t)(swz4(bnr, bslot) << 3);
    gl2lds16(w1h + go, (char*)&sBh[buf][0] + (wid << 10));
    gl2lds16(w1l + go, (char*)&sBl[buf][0] + (wid << 10));
  };
  auto LOAD_A = [&](int kkv) {
    int gk = (chunk << 10) + ((kkv & 31) << 5);
    int f = gk >> 9, off = (gk & 255) + (ac4 << 2);
    const float* xb = ((gk >> 8) & 1) ? varp : meanp;
#pragma unroll
    for (int p = 0; p < 2; ++p) {
      int row = ar + (p << 6);
      fly[p] = *(const float4*)(xb + ((size_t)(bm + row) * NF + f) * ND + off);
    }
  };
  auto WRITE_A = [&](int buf) {
#pragma unroll
    for (int p = 0; p < 2; ++p) {
      int row = ar + (p << 6);
      float4 v = fly[p];
      f16 h0 = (f16)v.x, h1 = (f16)v.y, h2 = (f16)v.z, h3 = (f16)v.w;
      f16x4 hv = {h0, h1, h2, h3};
      f16x4 lv = {(f16)((v.x - (float)h0) * LSCALE), (f16)((v.y - (float)h1) * LSCALE),
                  (f16)((v.z - (float)h2) * LSCALE), (f16)((v.w - (float)h3) * LSCALE)};
      int byte = (row << 6) + (swz4(row, ac4 >> 1) << 4) + ((ac4 & 1) << 3);
      *(f16x4*)((char*)&sAh[buf][0] + byte) = hv;
      *(f16x4*)((char*)&sAl[buf][0] + byte) = lv;
    }
  };

  STAGE_B(0, 0);
  LOAD_A(0);
  WRITE_A(0);
  LOAD_A(1);
  __syncthreads();

  int cur = 0;
  for (int kk = 0; kk < 32; ++kk) {
    int nxt = cur ^ 1;
    STAGE_B(kk + 1, nxt);
    WRITE_A(nxt);
    LOAD_A(kk + 2);
    f16x8 ah[2], al[2], bh[4], bl[4];
#pragma unroll
    for (int m = 0; m < 2; ++m) {
      int row = (wr << 5) + (m << 4) + lr;
      int byte = (row << 6) + (swz4(row, lk) << 4);
      ah[m] = *(const f16x8*)((const char*)&sAh[cur][0] + byte);
      al[m] = *(const f16x8*)((const char*)&sAl[cur][0] + byte);
    }
#pragma unroll
    for (int n = 0; n < 4; ++n) {
      int col = (wc << 6) + (n << 4) + lr;
      int byte = (col << 6) + (swz4(col, lk) << 4);
      bh[n] = *(const f16x8*)((const char*)&sBh[cur][0] + byte);
      bl[n] = *(const f16x8*)((const char*)&sBl[cur][0] + byte);
    }
#pragma unroll
    for (int m = 0; m < 2; ++m)
#pragma unroll
      for (int n = 0; n < 4; ++n) {
        acc0[m][n] = __builtin_amdgcn_mfma_f32_16x16x32_f16(ah[m], bh[n], acc0[m][n], 0, 0, 0);
        acc1[m][n] = __builtin_amdgcn_mfma_f32_16x16x32_f16(ah[m], bl[n], acc1[m][n], 0, 0, 0);
        acc1[m][n] = __builtin_amdgcn_mfma_f32_16x16x32_f16(al[m], bh[n], acc1[m][n], 0, 0, 0);
      }
    __syncthreads();
    cur = nxt;
  }
  float* po = partial + (size_t)chunk * NB * ND;
#pragma unroll
  for (int m = 0; m < 2; ++m)
#pragma unroll
    for (int n = 0; n < 4; ++n)
#pragma unroll
      for (int r = 0; r < 4; ++r)
        po[(size_t)(bm + (wr << 5) + (m << 4) + (lk << 2) + r) * ND + bn + (wc << 6) + (n << 4) + lr] =
            (acc0[m][n][r] + acc1[m][n][r] * INV_LS) * INV_WS;
}

__device__ __forceinline__ double block_sum_f64(double v, double* sred) {
#pragma unroll
  for (int m = 32; m >= 1; m >>= 1) v += __shfl_xor(v, m);
  __syncthreads();
  if ((threadIdx.x & 63) == 0) sred[threadIdx.x >> 6] = v;
  __syncthreads();
  return sred[0] + sred[1] + sred[2] + sred[3];
}

// ---------------- reduce + f64 GELU/LN/selection; flag row iff cut-gap a[85]-a[86] < M ----------------
__global__ __launch_bounds__(256) void reduce_ln_kwta(const float* __restrict__ partial, const float* __restrict__ b1,
                                                      const float* __restrict__ gamma, const float* __restrict__ beta,
                                                      f16* __restrict__ hh, f16* __restrict__ hl,
                                                      int* __restrict__ flags) {
  int b = blockIdx.x, d = threadIdx.x;
  double s = 0.0;
#pragma unroll
  for (int c = 0; c < 32; ++c) s += (double)partial[((size_t)c * NB + b) * ND + d];
  s += (double)b1[d];
  double g = 0.5 * s * (1.0 + erf(s * 0.70710678118654752440));
  __shared__ double sredd[4];
  double mu = block_sum_f64(g, sredd) * (1.0 / 256.0);
  double dv = g - mu;
  double var = block_sum_f64(dv * dv, sredd) * (1.0 / 256.0);
  double hn = dv * (1.0 / sqrt(var + 1e-3)) * (double)gamma[d] + (double)beta[d];
  double a = fabs(hn);
  __shared__ double as_[256];
  as_[d] = a;
  __syncthreads();
  int cnt_ex = 0;
  for (int j = 0; j < 256; ++j) {
    double aj = as_[j];
    cnt_ex += ((aj > a) || (aj == a && j < d)) ? 1 : 0;
  }
  __shared__ double a85, a86;
  if (cnt_ex == KWIN - 1) a85 = a;
  if (cnt_ex == KWIN) a86 = a;
  __syncthreads();
  const double M = 2e-5;  // >=20 sigma of fp16x3 GEMM noise in a-units
  if (d == 0 && (a85 - a86 < M)) {
    int slot = atomicAdd(&flags[0], 1);
    if (slot < MAXFIX) flags[1 + slot] = b;
  }
  float hv = (cnt_ex < KWIN) ? (float)hn : 0.f;
  f16 h = (f16)hv;
  size_t o = (size_t)b * ND + d;
  hh[o] = h;
  hl[o] = (f16)((hv - (float)h) * LSCALE);
}

// ---------------- fixup pass 1: exact GEMV for flagged rows (two-prod -> f64 accum) ----------------
__global__ __launch_bounds__(256) void fixup_gemv(const float* __restrict__ meanp, const float* __restrict__ varp,
                                                  const float* __restrict__ W1, const int* __restrict__ flags,
                                                  double* __restrict__ p64) {
  int nf = flags[0]; if (nf > MAXFIX) nf = MAXFIX;
  int slot = blockIdx.x >> 6;
  int kb = blockIdx.x & (FKB - 1);
  if (slot >= nf) return;
  int r = flags[1 + slot];
  int t = threadIdx.x;
  __shared__ float xs[512];
  int k0 = kb << 9;
  for (int i = t; i < 512; i += 256) {
    const float* xb = (i & 256) ? varp : meanp;
    xs[i] = xb[(((size_t)r * NF + kb) << 8) + (i & 255)];
  }
  __syncthreads();
  double accp0 = 0.0, accp1 = 0.0, acce0 = 0.0, acce1 = 0.0;
  const float* wcol = W1 + (size_t)k0 * ND + t;
#pragma unroll 8
  for (int i = 0; i < 512; i += 2) {
    float x0 = xs[i], w0 = wcol[(size_t)i * ND];
    float x1 = xs[i + 1], w1 = wcol[(size_t)(i + 1) * ND];
    float p0 = x0 * w0, p1 = x1 * w1;
    float e0 = fmaf(x0, w0, -p0), e1 = fmaf(x1, w1, -p1);
    accp0 += (double)p0;
    accp1 += (double)p1;
    acce0 += (double)e0;
    acce1 += (double)e1;
  }
  p64[((size_t)slot * FKB + kb) * ND + t] = (accp0 + accp1) + (acce0 + acce1);
}

// ---------------- fixup pass 2: f64 GELU + LN + exact kWTA for flagged rows ----------------
__global__ __launch_bounds__(256) void fixup_ln_kwta(const double* __restrict__ p64, const float* __restrict__ b1,
                                                     const float* __restrict__ gamma, const float* __restrict__ beta,
                                                     const int* __restrict__ flags,
                                                     f16* __restrict__ hh, f16* __restrict__ hl) {
  int nf = flags[0]; if (nf > MAXFIX) nf = MAXFIX;
  int slot = blockIdx.x;
  if (slot >= nf) return;
  int r = flags[1 + slot];
  int d = threadIdx.x;
  double s = 0.0;
#pragma unroll
  for (int kb = 0; kb < FKB; ++kb) s += p64[((size_t)slot * FKB + kb) * ND + d];
  s += (double)b1[d];
  double g = 0.5 * s * (1.0 + erf(s * 0.70710678118654752440));
  __shared__ double sredd[4];
  double mu = block_sum_f64(g, sredd) * (1.0 / 256.0);
  double dv = g - mu;
  double var = block_sum_f64(dv * dv, sredd) * (1.0 / 256.0);
  double hn = dv * (1.0 / sqrt(var + 1e-3)) * (double)gamma[d] + (double)beta[d];
  double a = fabs(hn);
  __shared__ double as_[256];
  as_[d] = a;
  __syncthreads();
  int cnt = 0;
  for (int j = 0; j < 256; ++j) {
    double aj = as_[j];
    cnt += ((aj > a) || (aj == a && j < d)) ? 1 : 0;
  }
  double hvd = (cnt < KWIN) ? hn : 0.0;
  float hf = (float)hvd;
  f16 h = (f16)hf;
  size_t o = (size_t)r * ND + d;
  hh[o] = h;
  hl[o] = (f16)((hf - (float)h) * LSCALE);
}

// ---------------- GEMM2: BM=128 x BN=128, 512 thr / 8 waves, BK=32 double-buffered 2-phase ----------------
// out = tanh(h @ W2 + b2); fp16x3 dual-acc; 32 out/thread = 64 acc VGPR (gemm1's proven profile).
__global__ __launch_bounds__(512, 4) void gemm2_kernel(const f16* __restrict__ hh, const f16* __restrict__ hl,
                                                       const f16* __restrict__ w2h, const f16* __restrict__ w2l,
                                                       const float* __restrict__ b2, float* __restrict__ outp) {
  __shared__ alignas(16) f16 sAh[2][128 * 32], sAl[2][128 * 32];
  __shared__ alignas(16) f16 sBh[2][128 * 32], sBl[2][128 * 32];
  int t = threadIdx.x;
  int bm = (blockIdx.x & 7) << 7;
  int bn = (blockIdx.x >> 3) << 7;
  int wid = t >> 6, lane = t & 63, lr = lane & 15, lk = lane >> 4;
  int wr = wid >> 1, wc = wid & 1;  // wave tile 32x64
  f32x4 acc0[2][4] = {};
  f32x4 acc1[2][4] = {};
  int anr = t >> 2, aslot = t & 3;  // staging: 128 rows x 4 slots, 1 gl2lds16/thread/array

  auto STAGE = [&](int sv, int buf) {
    int k0 = (sv & 7) << 5;
    size_t goa = (size_t)(bm + anr) * ND + k0 + (size_t)(swz4(anr, aslot) << 3);
    size_t gob = (size_t)(bn + anr) * ND + k0 + (size_t)(swz4(anr, aslot) << 3);
    gl2lds16(hh + goa, (char*)&sAh[buf][0] + (wid << 10));
    gl2lds16(hl + goa, (char*)&sAl[buf][0] + (wid << 10));
    gl2lds16(w2h + gob, (char*)&sBh[buf][0] + (wid << 10));
    gl2lds16(w2l + gob, (char*)&sBl[buf][0] + (wid << 10));
  };

  STAGE(0, 0);
  __syncthreads();

  int cur = 0;
  for (int s = 0; s < 8; ++s) {
    int nxt = cur ^ 1;
    STAGE(s + 1, nxt);  // wraps harmlessly on last iter
    f16x8 ah[2], al[2], bh[4], bl[4];
#pragma unroll
    for (int m = 0; m < 2; ++m) {
      int row = (wr << 5) + (m << 4) + lr;
      int byte = (row << 6) + (swz4(row, lk) << 4);
      ah[m] = *(const f16x8*)((const char*)&sAh[cur][0] + byte);
      al[m] = *(const f16x8*)((const char*)&sAl[cur][0] + byte);
    }
#pragma unroll
    for (int n = 0; n < 4; ++n) {
      int col = (wc << 6) + (n << 4) + lr;
      int byte = (col << 6) + (swz4(col, lk) << 4);
      bh[n] = *(const f16x8*)((const char*)&sBh[cur][0] + byte);
      bl[n] = *(const f16x8*)((const char*)&sBl[cur][0] + byte);
    }
#pragma unroll
    for (int m = 0; m < 2; ++m)
#pragma unroll
      for (int n = 0; n < 4; ++n) {
        acc0[m][n] = __builtin_amdgcn_mfma_f32_16x16x32_f16(ah[m], bh[n], acc0[m][n], 0, 0, 0);
        acc1[m][n] = __builtin_amdgcn_mfma_f32_16x16x32_f16(ah[m], bl[n], acc1[m][n], 0, 0, 0);
        acc1[m][n] = __builtin_amdgcn_mfma_f32_16x16x32_f16(al[m], bh[n], acc1[m][n], 0, 0, 0);
      }
    __syncthreads();
    cur = nxt;
  }
#pragma unroll
  for (int m = 0; m < 2; ++m)
#pragma unroll
    for (int n = 0; n < 4; ++n)
#pragma unroll
      for (int r = 0; r < 4; ++r) {
        int row = bm + (wr << 5) + (m << 4) + (lk << 2) + r;
        int col = bn + (wc << 6) + (n << 4) + lr;
        float val = (acc0[m][n][r] + acc1[m][n][r] * INV_LS) * INV_WS + b2[col];
        float av = fabsf(val);
        float e = __expf(-2.0f * av);
        float rr = (1.0f - e) / (1.0f + e);
        outp[(size_t)row * OUTC + col] = copysignf(rr, val);
      }
}

extern "C" void kernel_launch(void* const* d_in, const int* in_sizes, int n_in,
                              void* d_out, int out_size, void* d_ws, size_t ws_size,
                              hipStream_t stream) {
  (void)in_sizes; (void)n_in; (void)out_size; (void)ws_size;
  const float* meanp = (const float*)d_in[0];
  const float* varp  = (const float*)d_in[1];
  const float* W1    = (const float*)d_in[2];
  const float* b1    = (const float*)d_in[3];
  const float* gamma = (const float*)d_in[4];
  const float* beta  = (const float*)d_in[5];
  const float* W2    = (const float*)d_in[6];
  const float* b2    = (const float*)d_in[7];
  float* outp = (float*)d_out;
  char* ws = (char*)d_ws;

  f16* w1h = (f16*)(ws);                              // 16 MiB: [256][32768]
  f16* w1l = (f16*)(ws + ((size_t)16 << 20));         // 16 MiB
  f16* w2h = (f16*)(ws + ((size_t)32 << 20));         // 4 MiB: [8192][256]
  f16* w2l = (f16*)(ws + ((size_t)36 << 20));         // 4 MiB
  float* partial = (float*)(ws + ((size_t)40 << 20)); // 32 MiB: [32][1024][256]
  double* p64 = (double*)(ws + ((size_t)40 << 20));   // 4.2 MiB, aliases partial (consumed before use)
  f16* hh = (f16*)(ws + ((size_t)72 << 20));          // 512 KiB
  f16* hl = (f16*)(ws + ((size_t)72 << 20) + ((size_t)512 << 10)); // 512 KiB
  int* flags = (int*)(ws + ((size_t)73 << 20));       // nflag + rows[MAXFIX]

  hipMemsetAsync(flags, 0, (1 + MAXFIX) * sizeof(int), stream);
  transpose_split2<<<2560, 256, 0, stream>>>(W1, w1h, w1l, W2, w2h, w2l);
  gemm1_kernel<<<512, 512, 0, stream>>>(meanp, varp, w1h, w1l, partial);
  reduce_ln_kwta<<<NB, 256, 0, stream>>>(partial, b1, gamma, beta, hh, hl, flags);
  fixup_gemv<<<MAXFIX * FKB, 256, 0, stream>>>(meanp, varp, W1, flags, p64);
  fixup_ln_kwta<<<MAXFIX, 256, 0, stream>>>(p64, b1, gamma, beta, flags, hh, hl);
  gemm2_kernel<<<512, 512, 0, stream>>>(hh, hl, w2h, w2l, b2, outp);
}

// Round 18
// 168.418 us; speedup vs baseline: 1.1118x; 1.1118x over previous
//
#include <hip/hip_runtime.h>

typedef _Float16 f16;
typedef f16 f16x4 __attribute__((ext_vector_type(4)));
typedef f16 f16x8 __attribute__((ext_vector_type(8)));
typedef float f32x4 __attribute__((ext_vector_type(4)));

#define NB 1024
#define NF 64
#define ND 256
#define KWIN 85
#define INDIM 32768
#define OUTC 8192
#define MAXFIX 16
#define FKB 64  // k-chunks per flagged row in fixup pass 1 (512 k each)
// W pre-scaled by 256; lo-parts scaled by 2048; undone in f32 epilogues.
#define WSCALE 256.0f
#define LSCALE 2048.0f
#define INV_WS (1.0f / 256.0f)
#define INV_LS (1.0f / 2048.0f)

__device__ __forceinline__ int swz4(int row, int slot) { return slot ^ ((row ^ (row >> 2)) & 3); }

__device__ __forceinline__ void gl2lds16(const void* g, void* l) {
  __builtin_amdgcn_global_load_lds((const __attribute__((address_space(1))) void*)g,
                                   (__attribute__((address_space(3))) void*)l, 16, 0, 0);
}

// ---------------- merged transpose + fp16 hi/lo-scaled split for W1 and W2 (+ flags zeroing) ----------------
// bid < 2048: W1 (32768x256 -> w1T[256][32768]); bid >= 2048: W2 (256x8192 -> w2T[8192][256])
__global__ __launch_bounds__(256) void transpose_split2(const float* __restrict__ W1src,
                                                        f16* __restrict__ w1h, f16* __restrict__ w1l,
                                                        const float* __restrict__ W2src,
                                                        f16* __restrict__ w2h, f16* __restrict__ w2l,
                                                        int* __restrict__ flags) {
  __shared__ float tile[64][65];
  int bid = blockIdx.x;
  if (bid == 0 && threadIdx.x <= MAXFIX) flags[threadIdx.x] = 0;  // transpose completes before reduce runs
  const float* src;
  f16 *dhi, *dlo;
  int R, C;
  if (bid < 2048) {
    src = W1src; dhi = w1h; dlo = w1l; R = INDIM; C = ND;
  } else {
    bid -= 2048;
    src = W2src; dhi = w2h; dlo = w2l; R = ND; C = OUTC;
  }
  int t = threadIdx.x;
  int tiles_c = C >> 6;
  int tr = bid / tiles_c, tc = bid - tr * tiles_c;
  size_t r0 = (size_t)tr << 6;
  int c0 = tc << 6;
  int rr = t >> 4, cc = (t & 15) << 2;
#pragma unroll
  for (int p = 0; p < 4; ++p) {
    const float4 v = *(const float4*)(src + (r0 + (p << 4) + rr) * C + c0 + cc);
    tile[(p << 4) + rr][cc + 0] = v.x;
    tile[(p << 4) + rr][cc + 1] = v.y;
    tile[(p << 4) + rr][cc + 2] = v.z;
    tile[(p << 4) + rr][cc + 3] = v.w;
  }
  __syncthreads();
  int n = t >> 2, kq = t & 3;
  alignas(16) f16 hv[16];
  alignas(16) f16 lv[16];
#pragma unroll
  for (int e = 0; e < 16; ++e) {
    float x = tile[(kq << 4) + e][n] * WSCALE;
    f16 h = (f16)x;
    hv[e] = h;
    lv[e] = (f16)((x - (float)h) * LSCALE);
  }
  size_t ob = (size_t)(c0 + n) * (size_t)R + r0 + (kq << 4);
  *(f16x8*)(dhi + ob)     = *(const f16x8*)&hv[0];
  *(f16x8*)(dhi + ob + 8) = *(const f16x8*)&hv[8];
  *(f16x8*)(dlo + ob)     = *(const f16x8*)&lv[0];
  *(f16x8*)(dlo + ob + 8) = *(const f16x8*)&lv[8];
}

// ---------------- GEMM1: BM=128 x BN=128, 512 thr, 2 blk/CU, 2-phase dbuf (template floor: 536 MB staged) ----------------
__global__ __launch_bounds__(512, 4) void gemm1_kernel(const float* __restrict__ meanp, const float* __restrict__ varp,
                                                       const f16* __restrict__ w1h, const f16* __restrict__ w1l,
                                                       float* __restrict__ partial) {
  __shared__ alignas(16) f16 sAh[2][128 * 32], sAl[2][128 * 32];
  __shared__ alignas(16) f16 sBh[2][128 * 32], sBl[2][128 * 32];
  int t = threadIdx.x;
  int chunk = blockIdx.x & 31;
  int nb = (blockIdx.x >> 5) & 1;
  int rb = blockIdx.x >> 6;
  int bm = rb << 7, bn = nb << 7;
  int wid = t >> 6, lane = t & 63, lr = lane & 15, lk = lane >> 4;
  int wr = wid >> 1, wc = wid & 1;
  f32x4 acc0[2][4] = {};
  f32x4 acc1[2][4] = {};
  int ar = t >> 3, ac4 = t & 7;
  int bnr = t >> 2, bslot = t & 3;

  float4 fly[2];

  auto STAGE_B = [&](int kkv, int buf) {
    int gk = (chunk << 10) + ((kkv & 31) << 5);
    size_t go = (size_t)(bn + bnr) * INDIM + (size_t)gk + (size_t)(swz4(bnr, bslot) << 3);
    gl2lds16(w1h + go, (char*)&sBh[buf][0] + (wid << 10));
    gl2lds16(w1l + go, (char*)&sBl[buf][0] + (wid << 10));
  };
  auto LOAD_A = [&](int kkv) {
    int gk = (chunk << 10) + ((kkv & 31) << 5);
    int f = gk >> 9, off = (gk & 255) + (ac4 << 2);
    const float* xb = ((gk >> 8) & 1) ? varp : meanp;
#pragma unroll
    for (int p = 0; p < 2; ++p) {
      int row = ar + (p << 6);
      fly[p] = *(const float4*)(xb + ((size_t)(bm + row) * NF + f) * ND + off);
    }
  };
  auto WRITE_A = [&](int buf) {
#pragma unroll
    for (int p = 0; p < 2; ++p) {
      int row = ar + (p << 6);
      float4 v = fly[p];
      f16 h0 = (f16)v.x, h1 = (f16)v.y, h2 = (f16)v.z, h3 = (f16)v.w;
      f16x4 hv = {h0, h1, h2, h3};
      f16x4 lv = {(f16)((v.x - (float)h0) * LSCALE), (f16)((v.y - (float)h1) * LSCALE),
                  (f16)((v.z - (float)h2) * LSCALE), (f16)((v.w - (float)h3) * LSCALE)};
      int byte = (row << 6) + (swz4(row, ac4 >> 1) << 4) + ((ac4 & 1) << 3);
      *(f16x4*)((char*)&sAh[buf][0] + byte) = hv;
      *(f16x4*)((char*)&sAl[buf][0] + byte) = lv;
    }
  };

  STAGE_B(0, 0);
  LOAD_A(0);
  WRITE_A(0);
  LOAD_A(1);
  __syncthreads();

  int cur = 0;
  for (int kk = 0; kk < 32; ++kk) {
    int nxt = cur ^ 1;
    STAGE_B(kk + 1, nxt);
    WRITE_A(nxt);
    LOAD_A(kk + 2);
    f16x8 ah[2], al[2], bh[4], bl[4];
#pragma unroll
    for (int m = 0; m < 2; ++m) {
      int row = (wr << 5) + (m << 4) + lr;
      int byte = (row << 6) + (swz4(row, lk) << 4);
      ah[m] = *(const f16x8*)((const char*)&sAh[cur][0] + byte);
      al[m] = *(const f16x8*)((const char*)&sAl[cur][0] + byte);
    }
#pragma unroll
    for (int n = 0; n < 4; ++n) {
      int col = (wc << 6) + (n << 4) + lr;
      int byte = (col << 6) + (swz4(col, lk) << 4);
      bh[n] = *(const f16x8*)((const char*)&sBh[cur][0] + byte);
      bl[n] = *(const f16x8*)((const char*)&sBl[cur][0] + byte);
    }
#pragma unroll
    for (int m = 0; m < 2; ++m)
#pragma unroll
      for (int n = 0; n < 4; ++n) {
        acc0[m][n] = __builtin_amdgcn_mfma_f32_16x16x32_f16(ah[m], bh[n], acc0[m][n], 0, 0, 0);
        acc1[m][n] = __builtin_amdgcn_mfma_f32_16x16x32_f16(ah[m], bl[n], acc1[m][n], 0, 0, 0);
        acc1[m][n] = __builtin_amdgcn_mfma_f32_16x16x32_f16(al[m], bh[n], acc1[m][n], 0, 0, 0);
      }
    __syncthreads();
    cur = nxt;
  }
  float* po = partial + (size_t)chunk * NB * ND;
#pragma unroll
  for (int m = 0; m < 2; ++m)
#pragma unroll
    for (int n = 0; n < 4; ++n)
#pragma unroll
      for (int r = 0; r < 4; ++r)
        po[(size_t)(bm + (wr << 5) + (m << 4) + (lk << 2) + r) * ND + bn + (wc << 6) + (n << 4) + lr] =
            (acc0[m][n][r] + acc1[m][n][r] * INV_LS) * INV_WS;
}

__device__ __forceinline__ double block_sum_f64(double v, double* sred) {
#pragma unroll
  for (int m = 32; m >= 1; m >>= 1) v += __shfl_xor(v, m);
  __syncthreads();
  if ((threadIdx.x & 63) == 0) sred[threadIdx.x >> 6] = v;
  __syncthreads();
  return sred[0] + sred[1] + sred[2] + sred[3];
}

// ---------------- reduce + f64 GELU/LN/selection; flag row iff cut-gap a[85]-a[86] < M ----------------
__global__ __launch_bounds__(256) void reduce_ln_kwta(const float* __restrict__ partial, const float* __restrict__ b1,
                                                      const float* __restrict__ gamma, const float* __restrict__ beta,
                                                      f16* __restrict__ hh, f16* __restrict__ hl,
                                                      int* __restrict__ flags) {
  int b = blockIdx.x, d = threadIdx.x;
  double s = 0.0;
#pragma unroll
  for (int c = 0; c < 32; ++c) s += (double)partial[((size_t)c * NB + b) * ND + d];
  s += (double)b1[d];
  double g = 0.5 * s * (1.0 + erf(s * 0.70710678118654752440));
  __shared__ double sredd[4];
  double mu = block_sum_f64(g, sredd) * (1.0 / 256.0);
  double dv = g - mu;
  double var = block_sum_f64(dv * dv, sredd) * (1.0 / 256.0);
  double hn = dv * (1.0 / sqrt(var + 1e-3)) * (double)gamma[d] + (double)beta[d];
  double a = fabs(hn);
  __shared__ double as_[256];
  as_[d] = a;
  __syncthreads();
  int cnt_ex = 0;
  for (int j = 0; j < 256; ++j) {
    double aj = as_[j];
    cnt_ex += ((aj > a) || (aj == a && j < d)) ? 1 : 0;
  }
  __shared__ double a85, a86;
  if (cnt_ex == KWIN - 1) a85 = a;
  if (cnt_ex == KWIN) a86 = a;
  __syncthreads();
  const double M = 2e-5;  // >=20 sigma of fp16x3 GEMM noise in a-units
  if (d == 0 && (a85 - a86 < M)) {
    int slot = atomicAdd(&flags[0], 1);
    if (slot < MAXFIX) flags[1 + slot] = b;
  }
  float hv = (cnt_ex < KWIN) ? (float)hn : 0.f;
  f16 h = (f16)hv;
  size_t o = (size_t)b * ND + d;
  hh[o] = h;
  hl[o] = (f16)((hv - (float)h) * LSCALE);
}

// ---------------- fixup pass 1: exact GEMV for flagged rows (two-prod -> f64 accum) ----------------
__global__ __launch_bounds__(256) void fixup_gemv(const float* __restrict__ meanp, const float* __restrict__ varp,
                                                  const float* __restrict__ W1, const int* __restrict__ flags,
                                                  double* __restrict__ p64) {
  int nf = flags[0]; if (nf > MAXFIX) nf = MAXFIX;
  int slot = blockIdx.x >> 6;
  int kb = blockIdx.x & (FKB - 1);
  if (slot >= nf) return;
  int r = flags[1 + slot];
  int t = threadIdx.x;
  __shared__ float xs[512];
  int k0 = kb << 9;
  for (int i = t; i < 512; i += 256) {
    const float* xb = (i & 256) ? varp : meanp;
    xs[i] = xb[(((size_t)r * NF + kb) << 8) + (i & 255)];
  }
  __syncthreads();
  double accp0 = 0.0, accp1 = 0.0, acce0 = 0.0, acce1 = 0.0;
  const float* wcol = W1 + (size_t)k0 * ND + t;
#pragma unroll 8
  for (int i = 0; i < 512; i += 2) {
    float x0 = xs[i], w0 = wcol[(size_t)i * ND];
    float x1 = xs[i + 1], w1 = wcol[(size_t)(i + 1) * ND];
    float p0 = x0 * w0, p1 = x1 * w1;
    float e0 = fmaf(x0, w0, -p0), e1 = fmaf(x1, w1, -p1);
    accp0 += (double)p0;
    accp1 += (double)p1;
    acce0 += (double)e0;
    acce1 += (double)e1;
  }
  p64[((size_t)slot * FKB + kb) * ND + t] = (accp0 + accp1) + (acce0 + acce1);
}

// ---------------- fixup pass 2: f64 GELU + LN + exact kWTA for flagged rows ----------------
__global__ __launch_bounds__(256) void fixup_ln_kwta(const double* __restrict__ p64, const float* __restrict__ b1,
                                                     const float* __restrict__ gamma, const float* __restrict__ beta,
                                                     const int* __restrict__ flags,
                                                     f16* __restrict__ hh, f16* __restrict__ hl) {
  int nf = flags[0]; if (nf > MAXFIX) nf = MAXFIX;
  int slot = blockIdx.x;
  if (slot >= nf) return;
  int r = flags[1 + slot];
  int d = threadIdx.x;
  double s = 0.0;
#pragma unroll
  for (int kb = 0; kb < FKB; ++kb) s += p64[((size_t)slot * FKB + kb) * ND + d];
  s += (double)b1[d];
  double g = 0.5 * s * (1.0 + erf(s * 0.70710678118654752440));
  __shared__ double sredd[4];
  double mu = block_sum_f64(g, sredd) * (1.0 / 256.0);
  double dv = g - mu;
  double var = block_sum_f64(dv * dv, sredd) * (1.0 / 256.0);
  double hn = dv * (1.0 / sqrt(var + 1e-3)) * (double)gamma[d] + (double)beta[d];
  double a = fabs(hn);
  __shared__ double as_[256];
  as_[d] = a;
  __syncthreads();
  int cnt = 0;
  for (int j = 0; j < 256; ++j) {
    double aj = as_[j];
    cnt += ((aj > a) || (aj == a && j < d)) ? 1 : 0;
  }
  double hvd = (cnt < KWIN) ? hn : 0.0;
  float hf = (float)hvd;
  f16 h = (f16)hf;
  size_t o = (size_t)r * ND + d;
  hh[o] = h;
  hl[o] = (f16)((hf - (float)h) * LSCALE);
}

// ---------------- GEMM2: BM=128 x BN=128, 512 thr / 8 waves, BK=32 double-buffered 2-phase ----------------
__global__ __launch_bounds__(512, 4) void gemm2_kernel(const f16* __restrict__ hh, const f16* __restrict__ hl,
                                                       const f16* __restrict__ w2h, const f16* __restrict__ w2l,
                                                       const float* __restrict__ b2, float* __restrict__ outp) {
  __shared__ alignas(16) f16 sAh[2][128 * 32], sAl[2][128 * 32];
  __shared__ alignas(16) f16 sBh[2][128 * 32], sBl[2][128 * 32];
  int t = threadIdx.x;
  int bm = (blockIdx.x & 7) << 7;
  int bn = (blockIdx.x >> 3) << 7;
  int wid = t >> 6, lane = t & 63, lr = lane & 15, lk = lane >> 4;
  int wr = wid >> 1, wc = wid & 1;
  f32x4 acc0[2][4] = {};
  f32x4 acc1[2][4] = {};
  int anr = t >> 2, aslot = t & 3;

  auto STAGE = [&](int sv, int buf) {
    int k0 = (sv & 7) << 5;
    size_t goa = (size_t)(bm + anr) * ND + k0 + (size_t)(swz4(anr, aslot) << 3);
    size_t gob = (size_t)(bn + anr) * ND + k0 + (size_t)(swz4(anr, aslot) << 3);
    gl2lds16(hh + goa, (char*)&sAh[buf][0] + (wid << 10));
    gl2lds16(hl + goa, (char*)&sAl[buf][0] + (wid << 10));
    gl2lds16(w2h + gob, (char*)&sBh[buf][0] + (wid << 10));
    gl2lds16(w2l + gob, (char*)&sBl[buf][0] + (wid << 10));
  };

  STAGE(0, 0);
  __syncthreads();

  int cur = 0;
  for (int s = 0; s < 8; ++s) {
    int nxt = cur ^ 1;
    STAGE(s + 1, nxt);
    f16x8 ah[2], al[2], bh[4], bl[4];
#pragma unroll
    for (int m = 0; m < 2; ++m) {
      int row = (wr << 5) + (m << 4) + lr;
      int byte = (row << 6) + (swz4(row, lk) << 4);
      ah[m] = *(const f16x8*)((const char*)&sAh[cur][0] + byte);
      al[m] = *(const f16x8*)((const char*)&sAl[cur][0] + byte);
    }
#pragma unroll
    for (int n = 0; n < 4; ++n) {
      int col = (wc << 6) + (n << 4) + lr;
      int byte = (col << 6) + (swz4(col, lk) << 4);
      bh[n] = *(const f16x8*)((const char*)&sBh[cur][0] + byte);
      bl[n] = *(const f16x8*)((const char*)&sBl[cur][0] + byte);
    }
#pragma unroll
    for (int m = 0; m < 2; ++m)
#pragma unroll
      for (int n = 0; n < 4; ++n) {
        acc0[m][n] = __builtin_amdgcn_mfma_f32_16x16x32_f16(ah[m], bh[n], acc0[m][n], 0, 0, 0);
        acc1[m][n] = __builtin_amdgcn_mfma_f32_16x16x32_f16(ah[m], bl[n], acc1[m][n], 0, 0, 0);
        acc1[m][n] = __builtin_amdgcn_mfma_f32_16x16x32_f16(al[m], bh[n], acc1[m][n], 0, 0, 0);
      }
    __syncthreads();
    cur = nxt;
  }
#pragma unroll
  for (int m = 0; m < 2; ++m)
#pragma unroll
    for (int n = 0; n < 4; ++n)
#pragma unroll
      for (int r = 0; r < 4; ++r) {
        int row = bm + (wr << 5) + (m << 4) + (lk << 2) + r;
        int col = bn + (wc << 6) + (n << 4) + lr;
        float val = (acc0[m][n][r] + acc1[m][n][r] * INV_LS) * INV_WS + b2[col];
        float av = fabsf(val);
        float e = __expf(-2.0f * av);
        float rr = (1.0f - e) / (1.0f + e);
        outp[(size_t)row * OUTC + col] = copysignf(rr, val);
      }
}

extern "C" void kernel_launch(void* const* d_in, const int* in_sizes, int n_in,
                              void* d_out, int out_size, void* d_ws, size_t ws_size,
                              hipStream_t stream) {
  (void)in_sizes; (void)n_in; (void)out_size; (void)ws_size;
  const float* meanp = (const float*)d_in[0];
  const float* varp  = (const float*)d_in[1];
  const float* W1    = (const float*)d_in[2];
  const float* b1    = (const float*)d_in[3];
  const float* gamma = (const float*)d_in[4];
  const float* beta  = (const float*)d_in[5];
  const float* W2    = (const float*)d_in[6];
  const float* b2    = (const float*)d_in[7];
  float* outp = (float*)d_out;
  char* ws = (char*)d_ws;

  f16* w1h = (f16*)(ws);                              // 16 MiB: [256][32768]
  f16* w1l = (f16*)(ws + ((size_t)16 << 20));         // 16 MiB
  f16* w2h = (f16*)(ws + ((size_t)32 << 20));         // 4 MiB: [8192][256]
  f16* w2l = (f16*)(ws + ((size_t)36 << 20));         // 4 MiB
  float* partial = (float*)(ws + ((size_t)40 << 20)); // 32 MiB: [32][1024][256]
  double* p64 = (double*)(ws + ((size_t)40 << 20));   // 2.1 MiB, aliases partial (consumed before use)
  f16* hh = (f16*)(ws + ((size_t)72 << 20));          // 512 KiB
  f16* hl = (f16*)(ws + ((size_t)72 << 20) + ((size_t)512 << 10)); // 512 KiB
  int* flags = (int*)(ws + ((size_t)73 << 20));       // nflag + rows[MAXFIX]

  transpose_split2<<<2560, 256, 0, stream>>>(W1, w1h, w1l, W2, w2h, w2l, flags);
  gemm1_kernel<<<512, 512, 0, stream>>>(meanp, varp, w1h, w1l, partial);
  reduce_ln_kwta<<<NB, 256, 0, stream>>>(partial, b1, gamma, beta, hh, hl, flags);
  fixup_gemv<<<MAXFIX * FKB, 256, 0, stream>>>(meanp, varp, W1, flags, p64);
  fixup_ln_kwta<<<MAXFIX, 256, 0, stream>>>(p64, b1, gamma, beta, flags, hh, hl);
  gemm2_kernel<<<512, 512, 0, stream>>>(hh, hl, w2h, w2l, b2, outp);
}

// Round 20
// 159.920 us; speedup vs baseline: 1.1709x; 1.0531x over previous
//
#include <hip/hip_runtime.h>

typedef _Float16 f16;
typedef f16 f16x4 __attribute__((ext_vector_type(4)));
typedef f16 f16x8 __attribute__((ext_vector_type(8)));
typedef float f32x4 __attribute__((ext_vector_type(4)));

#define NB 1024
#define NF 64
#define ND 256
#define KWIN 85
#define INDIM 32768
#define OUTC 8192
#define MAXFIX 16
#define FKB 64  // k-chunks per flagged row in fixup pass 1 (512 k each)
// W pre-scaled by 256; lo-parts scaled by 2048; undone in f32 epilogues.
#define WSCALE 256.0f
#define LSCALE 2048.0f
#define INV_WS (1.0f / 256.0f)
#define INV_LS (1.0f / 2048.0f)

__device__ __forceinline__ int swz4(int row, int slot) { return slot ^ ((row ^ (row >> 2)) & 3); }

__device__ __forceinline__ void gl2lds16(const void* g, void* l) {
  __builtin_amdgcn_global_load_lds((const __attribute__((address_space(1))) void*)g,
                                   (__attribute__((address_space(3))) void*)l, 16, 0, 0);
}

// ---------------- merged transpose + fp16 hi/lo-scaled split for W1 and W2 (+ flags zeroing) ----------------
// bid < 2048: W1 -> w1T hi+lo; bid >= 2048: W2 -> w2T hi only (gemm2 is plain-f16; lo dropped)
__global__ __launch_bounds__(256) void transpose_split2(const float* __restrict__ W1src,
                                                        f16* __restrict__ w1h, f16* __restrict__ w1l,
                                                        const float* __restrict__ W2src,
                                                        f16* __restrict__ w2h,
                                                        int* __restrict__ flags) {
  __shared__ float tile[64][65];
  int bid = blockIdx.x;
  if (bid == 0 && threadIdx.x <= MAXFIX) flags[threadIdx.x] = 0;  // transpose completes before reduce runs
  const float* src;
  f16 *dhi, *dlo;
  int R, C;
  if (bid < 2048) {
    src = W1src; dhi = w1h; dlo = w1l; R = INDIM; C = ND;
  } else {
    bid -= 2048;
    src = W2src; dhi = w2h; dlo = nullptr; R = ND; C = OUTC;
  }
  int t = threadIdx.x;
  int tiles_c = C >> 6;
  int tr = bid / tiles_c, tc = bid - tr * tiles_c;
  size_t r0 = (size_t)tr << 6;
  int c0 = tc << 6;
  int rr = t >> 4, cc = (t & 15) << 2;
#pragma unroll
  for (int p = 0; p < 4; ++p) {
    const float4 v = *(const float4*)(src + (r0 + (p << 4) + rr) * C + c0 + cc);
    tile[(p << 4) + rr][cc + 0] = v.x;
    tile[(p << 4) + rr][cc + 1] = v.y;
    tile[(p << 4) + rr][cc + 2] = v.z;
    tile[(p << 4) + rr][cc + 3] = v.w;
  }
  __syncthreads();
  int n = t >> 2, kq = t & 3;
  alignas(16) f16 hv[16];
  alignas(16) f16 lv[16];
#pragma unroll
  for (int e = 0; e < 16; ++e) {
    float x = tile[(kq << 4) + e][n] * WSCALE;
    f16 h = (f16)x;
    hv[e] = h;
    lv[e] = (f16)((x - (float)h) * LSCALE);
  }
  size_t ob = (size_t)(c0 + n) * (size_t)R + r0 + (kq << 4);
  *(f16x8*)(dhi + ob)     = *(const f16x8*)&hv[0];
  *(f16x8*)(dhi + ob + 8) = *(const f16x8*)&hv[8];
  if (dlo) {
    *(f16x8*)(dlo + ob)     = *(const f16x8*)&lv[0];
    *(f16x8*)(dlo + ob + 8) = *(const f16x8*)&lv[8];
  }
}

// ---------------- GEMM1: BM=128 x BN=128, 512 thr, 2 blk/CU, 2-phase dbuf (template floor: 536 MB staged) ----------------
__global__ __launch_bounds__(512, 4) void gemm1_kernel(const float* __restrict__ meanp, const float* __restrict__ varp,
                                                       const f16* __restrict__ w1h, const f16* __restrict__ w1l,
                                                       float* __restrict__ partial) {
  __shared__ alignas(16) f16 sAh[2][128 * 32], sAl[2][128 * 32];
  __shared__ alignas(16) f16 sBh[2][128 * 32], sBl[2][128 * 32];
  int t = threadIdx.x;
  int chunk = blockIdx.x & 31;
  int nb = (blockIdx.x >> 5) & 1;
  int rb = blockIdx.x >> 6;
  int bm = rb << 7, bn = nb << 7;
  int wid = t >> 6, lane = t & 63, lr = lane & 15, lk = lane >> 4;
  int wr = wid >> 1, wc = wid & 1;
  f32x4 acc0[2][4] = {};
  f32x4 acc1[2][4] = {};
  int ar = t >> 3, ac4 = t & 7;
  int bnr = t >> 2, bslot = t & 3;

  float4 fly[2];

  auto STAGE_B = [&](int kkv, int buf) {
    int gk = (chunk << 10) + ((kkv & 31) << 5);
    size_t go = (size_t)(bn + bnr) * INDIM + (size_t)gk + (size_t)(swz4(bnr, bslot) << 3);
    gl2lds16(w1h + go, (char*)&sBh[buf][0] + (wid << 10));
    gl2lds16(w1l + go, (char*)&sBl[buf][0] + (wid << 10));
  };
  auto LOAD_A = [&](int kkv) {
    int gk = (chunk << 10) + ((kkv & 31) << 5);
    int f = gk >> 9, off = (gk & 255) + (ac4 << 2);
    const float* xb = ((gk >> 8) & 1) ? varp : meanp;
#pragma unroll
    for (int p = 0; p < 2; ++p) {
      int row = ar + (p << 6);
      fly[p] = *(const float4*)(xb + ((size_t)(bm + row) * NF + f) * ND + off);
    }
  };
  auto WRITE_A = [&](int buf) {
#pragma unroll
    for (int p = 0; p < 2; ++p) {
      int row = ar + (p << 6);
      float4 v = fly[p];
      f16 h0 = (f16)v.x, h1 = (f16)v.y, h2 = (f16)v.z, h3 = (f16)v.w;
      f16x4 hv = {h0, h1, h2, h3};
      f16x4 lv = {(f16)((v.x - (float)h0) * LSCALE), (f16)((v.y - (float)h1) * LSCALE),
                  (f16)((v.z - (float)h2) * LSCALE), (f16)((v.w - (float)h3) * LSCALE)};
      int byte = (row << 6) + (swz4(row, ac4 >> 1) << 4) + ((ac4 & 1) << 3);
      *(f16x4*)((char*)&sAh[buf][0] + byte) = hv;
      *(f16x4*)((char*)&sAl[buf][0] + byte) = lv;
    }
  };

  STAGE_B(0, 0);
  LOAD_A(0);
  WRITE_A(0);
  LOAD_A(1);
  __syncthreads();

  int cur = 0;
  for (int kk = 0; kk < 32; ++kk) {
    int nxt = cur ^ 1;
    STAGE_B(kk + 1, nxt);
    WRITE_A(nxt);
    LOAD_A(kk + 2);
    f16x8 ah[2], al[2], bh[4], bl[4];
#pragma unroll
    for (int m = 0; m < 2; ++m) {
      int row = (wr << 5) + (m << 4) + lr;
      int byte = (row << 6) + (swz4(row, lk) << 4);
      ah[m] = *(const f16x8*)((const char*)&sAh[cur][0] + byte);
      al[m] = *(const f16x8*)((const char*)&sAl[cur][0] + byte);
    }
#pragma unroll
    for (int n = 0; n < 4; ++n) {
      int col = (wc << 6) + (n << 4) + lr;
      int byte = (col << 6) + (swz4(col, lk) << 4);
      bh[n] = *(const f16x8*)((const char*)&sBh[cur][0] + byte);
      bl[n] = *(const f16x8*)((const char*)&sBl[cur][0] + byte);
    }
#pragma unroll
    for (int m = 0; m < 2; ++m)
#pragma unroll
      for (int n = 0; n < 4; ++n) {
        acc0[m][n] = __builtin_amdgcn_mfma_f32_16x16x32_f16(ah[m], bh[n], acc0[m][n], 0, 0, 0);
        acc1[m][n] = __builtin_amdgcn_mfma_f32_16x16x32_f16(ah[m], bl[n], acc1[m][n], 0, 0, 0);
        acc1[m][n] = __builtin_amdgcn_mfma_f32_16x16x32_f16(al[m], bh[n], acc1[m][n], 0, 0, 0);
      }
    __syncthreads();
    cur = nxt;
  }
  float* po = partial + (size_t)chunk * NB * ND;
#pragma unroll
  for (int m = 0; m < 2; ++m)
#pragma unroll
    for (int n = 0; n < 4; ++n)
#pragma unroll
      for (int r = 0; r < 4; ++r)
        po[(size_t)(bm + (wr << 5) + (m << 4) + (lk << 2) + r) * ND + bn + (wc << 6) + (n << 4) + lr] =
            (acc0[m][n][r] + acc1[m][n][r] * INV_LS) * INV_WS;
}

__device__ __forceinline__ double block_sum_f64(double v, double* sred) {
#pragma unroll
  for (int m = 32; m >= 1; m >>= 1) v += __shfl_xor(v, m);
  __syncthreads();
  if ((threadIdx.x & 63) == 0) sred[threadIdx.x >> 6] = v;
  __syncthreads();
  return sred[0] + sred[1] + sred[2] + sred[3];
}

// ---------------- reduce + f64 GELU/LN/selection (f64 erf REQUIRED: f32 erff flips selection, r19) ----------------
__global__ __launch_bounds__(256) void reduce_ln_kwta(const float* __restrict__ partial, const float* __restrict__ b1,
                                                      const float* __restrict__ gamma, const float* __restrict__ beta,
                                                      f16* __restrict__ hh,
                                                      int* __restrict__ flags) {
  int b = blockIdx.x, d = threadIdx.x;
  double s = 0.0;
#pragma unroll
  for (int c = 0; c < 32; ++c) s += (double)partial[((size_t)c * NB + b) * ND + d];
  s += (double)b1[d];
  double g = 0.5 * s * (1.0 + erf(s * 0.70710678118654752440));
  __shared__ double sredd[4];
  double mu = block_sum_f64(g, sredd) * (1.0 / 256.0);
  double dv = g - mu;
  double var = block_sum_f64(dv * dv, sredd) * (1.0 / 256.0);
  double hn = dv * (1.0 / sqrt(var + 1e-3)) * (double)gamma[d] + (double)beta[d];
  double a = fabs(hn);
  __shared__ double as_[256];
  as_[d] = a;
  __syncthreads();
  int cnt_ex = 0;
  for (int j = 0; j < 256; ++j) {
    double aj = as_[j];
    cnt_ex += ((aj > a) || (aj == a && j < d)) ? 1 : 0;
  }
  __shared__ double a85, a86;
  if (cnt_ex == KWIN - 1) a85 = a;
  if (cnt_ex == KWIN) a86 = a;
  __syncthreads();
  const double M = 2e-5;  // >=20 sigma of fp16x3 GEMM noise in a-units
  if (d == 0 && (a85 - a86 < M)) {
    int slot = atomicAdd(&flags[0], 1);
    if (slot < MAXFIX) flags[1 + slot] = b;
  }
  float hv = (cnt_ex < KWIN) ? (float)hn : 0.f;
  hh[(size_t)b * ND + d] = (f16)hv;
}

// ---------------- fixup pass 1: exact GEMV for flagged rows (two-prod -> f64 accum) ----------------
__global__ __launch_bounds__(256) void fixup_gemv(const float* __restrict__ meanp, const float* __restrict__ varp,
                                                  const float* __restrict__ W1, const int* __restrict__ flags,
                                                  double* __restrict__ p64) {
  int nf = flags[0]; if (nf > MAXFIX) nf = MAXFIX;
  int slot = blockIdx.x >> 6;
  int kb = blockIdx.x & (FKB - 1);
  if (slot >= nf) return;
  int r = flags[1 + slot];
  int t = threadIdx.x;
  __shared__ float xs[512];
  int k0 = kb << 9;
  for (int i = t; i < 512; i += 256) {
    const float* xb = (i & 256) ? varp : meanp;
    xs[i] = xb[(((size_t)r * NF + kb) << 8) + (i & 255)];
  }
  __syncthreads();
  double accp0 = 0.0, accp1 = 0.0, acce0 = 0.0, acce1 = 0.0;
  const float* wcol = W1 + (size_t)k0 * ND + t;
#pragma unroll 8
  for (int i = 0; i < 512; i += 2) {
    float x0 = xs[i], w0 = wcol[(size_t)i * ND];
    float x1 = xs[i + 1], w1 = wcol[(size_t)(i + 1) * ND];
    float p0 = x0 * w0, p1 = x1 * w1;
    float e0 = fmaf(x0, w0, -p0), e1 = fmaf(x1, w1, -p1);
    accp0 += (double)p0;
    accp1 += (double)p1;
    acce0 += (double)e0;
    acce1 += (double)e1;
  }
  p64[((size_t)slot * FKB + kb) * ND + t] = (accp0 + accp1) + (acce0 + acce1);
}

// ---------------- fixup pass 2: f64 GELU + LN + exact kWTA for flagged rows ----------------
__global__ __launch_bounds__(256) void fixup_ln_kwta(const double* __restrict__ p64, const float* __restrict__ b1,
                                                     const float* __restrict__ gamma, const float* __restrict__ beta,
                                                     const int* __restrict__ flags,
                                                     f16* __restrict__ hh) {
  int nf = flags[0]; if (nf > MAXFIX) nf = MAXFIX;
  int slot = blockIdx.x;
  if (slot >= nf) return;
  int r = flags[1 + slot];
  int d = threadIdx.x;
  double s = 0.0;
#pragma unroll
  for (int kb = 0; kb < FKB; ++kb) s += p64[((size_t)slot * FKB + kb) * ND + d];
  s += (double)b1[d];
  double g = 0.5 * s * (1.0 + erf(s * 0.70710678118654752440));
  __shared__ double sredd[4];
  double mu = block_sum_f64(g, sredd) * (1.0 / 256.0);
  double dv = g - mu;
  double var = block_sum_f64(dv * dv, sredd) * (1.0 / 256.0);
  double hn = dv * (1.0 / sqrt(var + 1e-3)) * (double)gamma[d] + (double)beta[d];
  double a = fabs(hn);
  __shared__ double as_[256];
  as_[d] = a;
  __syncthreads();
  int cnt = 0;
  for (int j = 0; j < 256; ++j) {
    double aj = as_[j];
    cnt += ((aj > a) || (aj == a && j < d)) ? 1 : 0;
  }
  double hvd = (cnt < KWIN) ? hn : 0.0;
  hh[(size_t)r * ND + d] = (f16)(float)hvd;
}

// ---------------- GEMM2: plain f16 (hi x hi); output noise ~2e-3 << 0.02 threshold. 2-phase dbuf ----------------
__global__ __launch_bounds__(512, 4) void gemm2_kernel(const f16* __restrict__ hh,
                                                       const f16* __restrict__ w2h,
                                                       const float* __restrict__ b2, float* __restrict__ outp) {
  __shared__ alignas(16) f16 sAh[2][128 * 32];
  __shared__ alignas(16) f16 sBh[2][128 * 32];
  int t = threadIdx.x;
  int bm = (blockIdx.x & 7) << 7;
  int bn = (blockIdx.x >> 3) << 7;
  int wid = t >> 6, lane = t & 63, lr = lane & 15, lk = lane >> 4;
  int wr = wid >> 1, wc = wid & 1;
  f32x4 acc0[2][4] = {};
  int anr = t >> 2, aslot = t & 3;

  auto STAGE = [&](int sv, int buf) {
    int k0 = (sv & 7) << 5;
    size_t goa = (size_t)(bm + anr) * ND + k0 + (size_t)(swz4(anr, aslot) << 3);
    size_t gob = (size_t)(bn + anr) * ND + k0 + (size_t)(swz4(anr, aslot) << 3);
    gl2lds16(hh + goa, (char*)&sAh[buf][0] + (wid << 10));
    gl2lds16(w2h + gob, (char*)&sBh[buf][0] + (wid << 10));
  };

  STAGE(0, 0);
  __syncthreads();

  int cur = 0;
  for (int s = 0; s < 8; ++s) {
    int nxt = cur ^ 1;
    STAGE(s + 1, nxt);
    f16x8 ah[2], bh[4];
#pragma unroll
    for (int m = 0; m < 2; ++m) {
      int row = (wr << 5) + (m << 4) + lr;
      int byte = (row << 6) + (swz4(row, lk) << 4);
      ah[m] = *(const f16x8*)((const char*)&sAh[cur][0] + byte);
    }
#pragma unroll
    for (int n = 0; n < 4; ++n) {
      int col = (wc << 6) + (n << 4) + lr;
      int byte = (col << 6) + (swz4(col, lk) << 4);
      bh[n] = *(const f16x8*)((const char*)&sBh[cur][0] + byte);
    }
#pragma unroll
    for (int m = 0; m < 2; ++m)
#pragma unroll
      for (int n = 0; n < 4; ++n)
        acc0[m][n] = __builtin_amdgcn_mfma_f32_16x16x32_f16(ah[m], bh[n], acc0[m][n], 0, 0, 0);
    __syncthreads();
    cur = nxt;
  }
#pragma unroll
  for (int m = 0; m < 2; ++m)
#pragma unroll
    for (int n = 0; n < 4; ++n)
#pragma unroll
      for (int r = 0; r < 4; ++r) {
        int row = bm + (wr << 5) + (m << 4) + (lk << 2) + r;
        int col = bn + (wc << 6) + (n << 4) + lr;
        float val = acc0[m][n][r] * INV_WS + b2[col];
        float av = fabsf(val);
        float e = __expf(-2.0f * av);
        float rr = (1.0f - e) / (1.0f + e);
        outp[(size_t)row * OUTC + col] = copysignf(rr, val);
      }
}

extern "C" void kernel_launch(void* const* d_in, const int* in_sizes, int n_in,
                              void* d_out, int out_size, void* d_ws, size_t ws_size,
                              hipStream_t stream) {
  (void)in_sizes; (void)n_in; (void)out_size; (void)ws_size;
  const float* meanp = (const float*)d_in[0];
  const float* varp  = (const float*)d_in[1];
  const float* W1    = (const float*)d_in[2];
  const float* b1    = (const float*)d_in[3];
  const float* gamma = (const float*)d_in[4];
  const float* beta  = (const float*)d_in[5];
  const float* W2    = (const float*)d_in[6];
  const float* b2    = (const float*)d_in[7];
  float* outp = (float*)d_out;
  char* ws = (char*)d_ws;

  f16* w1h = (f16*)(ws);                              // 16 MiB: [256][32768]
  f16* w1l = (f16*)(ws + ((size_t)16 << 20));         // 16 MiB
  f16* w2h = (f16*)(ws + ((size_t)32 << 20));         // 4 MiB: [8192][256] (hi only)
  float* partial = (float*)(ws + ((size_t)40 << 20)); // 32 MiB: [32][1024][256]
  double* p64 = (double*)(ws + ((size_t)40 << 20));   // 2.1 MiB, aliases partial (consumed before use)
  f16* hh = (f16*)(ws + ((size_t)72 << 20));          // 512 KiB
  int* flags = (int*)(ws + ((size_t)73 << 20));       // nflag + rows[MAXFIX]

  transpose_split2<<<2560, 256, 0, stream>>>(W1, w1h, w1l, W2, w2h, flags);
  gemm1_kernel<<<512, 512, 0, stream>>>(meanp, varp, w1h, w1l, partial);
  reduce_ln_kwta<<<NB, 256, 0, stream>>>(partial, b1, gamma, beta, hh, flags);
  fixup_gemv<<<MAXFIX * FKB, 256, 0, stream>>>(meanp, varp, W1, flags, p64);
  fixup_ln_kwta<<<MAXFIX, 256, 0, stream>>>(p64, b1, gamma, beta, flags, hh);
  gemm2_kernel<<<512, 512, 0, stream>>>(hh, w2h, b2, outp);
}

// Round 22
// 158.937 us; speedup vs baseline: 1.1781x; 1.0062x over previous
//
#include <hip/hip_runtime.h>

typedef _Float16 f16;
typedef f16 f16x4 __attribute__((ext_vector_type(4)));
typedef f16 f16x8 __attribute__((ext_vector_type(8)));
typedef float f32x4 __attribute__((ext_vector_type(4)));

#define NB 1024
#define NF 64
#define ND 256
#define KWIN 85
#define INDIM 32768
#define OUTC 8192
#define MAXFIX 16
#define FKB 64  // k-chunks per flagged row in fixup pass 1 (512 k each)
// W pre-scaled by 256; lo-parts scaled by 2048; undone in f32 epilogues.
#define WSCALE 256.0f
#define LSCALE 2048.0f
#define INV_WS (1.0f / 256.0f)
#define INV_LS (1.0f / 2048.0f)

__device__ __forceinline__ int swz4(int row, int slot) { return slot ^ ((row ^ (row >> 2)) & 3); }

__device__ __forceinline__ void gl2lds16(const void* g, void* l) {
  __builtin_amdgcn_global_load_lds((const __attribute__((address_space(1))) void*)g,
                                   (__attribute__((address_space(3))) void*)l, 16, 0, 0);
}

// ---------------- merged transpose + fp16 hi/lo-scaled split for W1 and W2 (+ flags zeroing) ----------------
// bid < 2048: W1 -> w1T hi+lo; bid >= 2048: W2 -> w2T hi only (gemm2 is plain-f16; lo dropped)
__global__ __launch_bounds__(256) void transpose_split2(const float* __restrict__ W1src,
                                                        f16* __restrict__ w1h, f16* __restrict__ w1l,
                                                        const float* __restrict__ W2src,
                                                        f16* __restrict__ w2h,
                                                        int* __restrict__ flags) {
  __shared__ float tile[64][65];
  int bid = blockIdx.x;
  if (bid == 0 && threadIdx.x <= MAXFIX) flags[threadIdx.x] = 0;  // transpose completes before reduce runs
  const float* src;
  f16 *dhi, *dlo;
  int R, C;
  if (bid < 2048) {
    src = W1src; dhi = w1h; dlo = w1l; R = INDIM; C = ND;
  } else {
    bid -= 2048;
    src = W2src; dhi = w2h; dlo = nullptr; R = ND; C = OUTC;
  }
  int t = threadIdx.x;
  int tiles_c = C >> 6;
  int tr = bid / tiles_c, tc = bid - tr * tiles_c;
  size_t r0 = (size_t)tr << 6;
  int c0 = tc << 6;
  int rr = t >> 4, cc = (t & 15) << 2;
#pragma unroll
  for (int p = 0; p < 4; ++p) {
    const float4 v = *(const float4*)(src + (r0 + (p << 4) + rr) * C + c0 + cc);
    tile[(p << 4) + rr][cc + 0] = v.x;
    tile[(p << 4) + rr][cc + 1] = v.y;
    tile[(p << 4) + rr][cc + 2] = v.z;
    tile[(p << 4) + rr][cc + 3] = v.w;
  }
  __syncthreads();
  int n = t >> 2, kq = t & 3;
  alignas(16) f16 hv[16];
  alignas(16) f16 lv[16];
#pragma unroll
  for (int e = 0; e < 16; ++e) {
    float x = tile[(kq << 4) + e][n] * WSCALE;
    f16 h = (f16)x;
    hv[e] = h;
    lv[e] = (f16)((x - (float)h) * LSCALE);
  }
  size_t ob = (size_t)(c0 + n) * (size_t)R + r0 + (kq << 4);
  *(f16x8*)(dhi + ob)     = *(const f16x8*)&hv[0];
  *(f16x8*)(dhi + ob + 8) = *(const f16x8*)&hv[8];
  if (dlo) {
    *(f16x8*)(dlo + ob)     = *(const f16x8*)&lv[0];
    *(f16x8*)(dlo + ob + 8) = *(const f16x8*)&lv[8];
  }
}

// ---------------- GEMM1: BM=128 x BN=128, 256 thr / 4 waves of 64x64 (LDS-read traffic -25%) ----------------
// 2 blk/CU, 2-phase dbuf. Bit-identical math to r20 (same MFMA shape/K-order/swizzles; only wave mapping).
// r21 bug fixed: STAGE_B shot stride is 4096 B (i<<12), not 8192 (i<<13) which overran the buffer.
__global__ __launch_bounds__(256, 2) void gemm1_kernel(const float* __restrict__ meanp, const float* __restrict__ varp,
                                                       const f16* __restrict__ w1h, const f16* __restrict__ w1l,
                                                       float* __restrict__ partial) {
  __shared__ alignas(16) f16 sAh[2][128 * 32], sAl[2][128 * 32];  // 8 KB per buf per array
  __shared__ alignas(16) f16 sBh[2][128 * 32], sBl[2][128 * 32];  // 64 KB total
  int t = threadIdx.x;
  int chunk = blockIdx.x & 31;
  int nb = (blockIdx.x >> 5) & 1;
  int rb = blockIdx.x >> 6;
  int bm = rb << 7, bn = nb << 7;
  int wid = t >> 6, lane = t & 63, lr = lane & 15, lk = lane >> 4;
  int wr = wid >> 1, wc = wid & 1;  // 2x2 waves, wave tile 64x64
  f32x4 acc0[4][4] = {};
  f32x4 acc1[4][4] = {};
  int arow = t >> 1, as0 = (t & 1) << 1;  // A: row 0-127, two 16B f16-slots {as0, as0+1}
  int bcolb = t >> 2, bslot = t & 3;      // B: per shot i, col = i*64 + (t>>2), slot = t&3

  float4 fly[4];

  auto STAGE_B = [&](int kkv, int buf) {
    int gk = (chunk << 10) + ((kkv & 31) << 5);
#pragma unroll
    for (int i = 0; i < 2; ++i) {
      int col = (i << 6) + bcolb;
      size_t go = (size_t)(bn + col) * INDIM + (size_t)gk + (size_t)(swz4(col, bslot) << 3);
      gl2lds16(w1h + go, (char*)&sBh[buf][0] + (i << 12) + (wid << 10));
      gl2lds16(w1l + go, (char*)&sBl[buf][0] + (i << 12) + (wid << 10));
    }
  };
  auto LOAD_A = [&](int kkv) {
    int gk = (chunk << 10) + ((kkv & 31) << 5);
    int f = gk >> 9, off = gk & 255;
    const float* xb = ((gk >> 8) & 1) ? varp : meanp;
    const float* base = xb + ((size_t)(bm + arow) * NF + f) * ND + off;
#pragma unroll
    for (int j = 0; j < 2; ++j) {
      int s = as0 + j;
      fly[2 * j + 0] = *(const float4*)(base + (s << 3));
      fly[2 * j + 1] = *(const float4*)(base + (s << 3) + 4);
    }
  };
  auto WRITE_A = [&](int buf) {
#pragma unroll
    for (int j = 0; j < 2; ++j) {
      int s = as0 + j;
      float4 u = fly[2 * j + 0], v = fly[2 * j + 1];
      f16 h0 = (f16)u.x, h1 = (f16)u.y, h2 = (f16)u.z, h3 = (f16)u.w;
      f16 h4 = (f16)v.x, h5 = (f16)v.y, h6 = (f16)v.z, h7 = (f16)v.w;
      f16x8 hv = {h0, h1, h2, h3, h4, h5, h6, h7};
      f16x8 lv = {(f16)((u.x - (float)h0) * LSCALE), (f16)((u.y - (float)h1) * LSCALE),
                  (f16)((u.z - (float)h2) * LSCALE), (f16)((u.w - (float)h3) * LSCALE),
                  (f16)((v.x - (float)h4) * LSCALE), (f16)((v.y - (float)h5) * LSCALE),
                  (f16)((v.z - (float)h6) * LSCALE), (f16)((v.w - (float)h7) * LSCALE)};
      int byte = (arow << 6) + (swz4(arow, s) << 4);
      *(f16x8*)((char*)&sAh[buf][0] + byte) = hv;
      *(f16x8*)((char*)&sAl[buf][0] + byte) = lv;
    }
  };

  STAGE_B(0, 0);
  LOAD_A(0);
  WRITE_A(0);
  LOAD_A(1);
  __syncthreads();

  int cur = 0;
  for (int kk = 0; kk < 32; ++kk) {
    int nxt = cur ^ 1;
    STAGE_B(kk + 1, nxt);
    WRITE_A(nxt);
    LOAD_A(kk + 2);
    f16x8 ah[4], al[4], bh[4], bl[4];
#pragma unroll
    for (int m = 0; m < 4; ++m) {
      int row = (wr << 6) + (m << 4) + lr;
      int byte = (row << 6) + (swz4(row, lk) << 4);
      ah[m] = *(const f16x8*)((const char*)&sAh[cur][0] + byte);
      al[m] = *(const f16x8*)((const char*)&sAl[cur][0] + byte);
    }
#pragma unroll
    for (int n = 0; n < 4; ++n) {
      int col = (wc << 6) + (n << 4) + lr;
      int byte = (col << 6) + (swz4(col, lk) << 4);
      bh[n] = *(const f16x8*)((const char*)&sBh[cur][0] + byte);
      bl[n] = *(const f16x8*)((const char*)&sBl[cur][0] + byte);
    }
#pragma unroll
    for (int m = 0; m < 4; ++m)
#pragma unroll
      for (int n = 0; n < 4; ++n) {
        acc0[m][n] = __builtin_amdgcn_mfma_f32_16x16x32_f16(ah[m], bh[n], acc0[m][n], 0, 0, 0);
        acc1[m][n] = __builtin_amdgcn_mfma_f32_16x16x32_f16(ah[m], bl[n], acc1[m][n], 0, 0, 0);
        acc1[m][n] = __builtin_amdgcn_mfma_f32_16x16x32_f16(al[m], bh[n], acc1[m][n], 0, 0, 0);
      }
    __syncthreads();
    cur = nxt;
  }
  float* po = partial + (size_t)chunk * NB * ND;
#pragma unroll
  for (int m = 0; m < 4; ++m)
#pragma unroll
    for (int n = 0; n < 4; ++n)
#pragma unroll
      for (int r = 0; r < 4; ++r)
        po[(size_t)(bm + (wr << 6) + (m << 4) + (lk << 2) + r) * ND + bn + (wc << 6) + (n << 4) + lr] =
            (acc0[m][n][r] + acc1[m][n][r] * INV_LS) * INV_WS;
}

__device__ __forceinline__ double block_sum_f64(double v, double* sred) {
#pragma unroll
  for (int m = 32; m >= 1; m >>= 1) v += __shfl_xor(v, m);
  __syncthreads();
  if ((threadIdx.x & 63) == 0) sred[threadIdx.x >> 6] = v;
  __syncthreads();
  return sred[0] + sred[1] + sred[2] + sred[3];
}

// ---------------- reduce + f64 GELU/LN/selection (f64 erf REQUIRED: f32 erff flips selection, r19) ----------------
__global__ __launch_bounds__(256) void reduce_ln_kwta(const float* __restrict__ partial, const float* __restrict__ b1,
                                                      const float* __restrict__ gamma, const float* __restrict__ beta,
                                                      f16* __restrict__ hh,
                                                      int* __restrict__ flags) {
  int b = blockIdx.x, d = threadIdx.x;
  double s = 0.0;
#pragma unroll
  for (int c = 0; c < 32; ++c) s += (double)partial[((size_t)c * NB + b) * ND + d];
  s += (double)b1[d];
  double g = 0.5 * s * (1.0 + erf(s * 0.70710678118654752440));
  __shared__ double sredd[4];
  double mu = block_sum_f64(g, sredd) * (1.0 / 256.0);
  double dv = g - mu;
  double var = block_sum_f64(dv * dv, sredd) * (1.0 / 256.0);
  double hn = dv * (1.0 / sqrt(var + 1e-3)) * (double)gamma[d] + (double)beta[d];
  double a = fabs(hn);
  __shared__ double as_[256];
  as_[d] = a;
  __syncthreads();
  int cnt_ex = 0;
  for (int j = 0; j < 256; ++j) {
    double aj = as_[j];
    cnt_ex += ((aj > a) || (aj == a && j < d)) ? 1 : 0;
  }
  __shared__ double a85, a86;
  if (cnt_ex == KWIN - 1) a85 = a;
  if (cnt_ex == KWIN) a86 = a;
  __syncthreads();
  const double M = 2e-5;  // >=20 sigma of fp16x3 GEMM noise in a-units
  if (d == 0 && (a85 - a86 < M)) {
    int slot = atomicAdd(&flags[0], 1);
    if (slot < MAXFIX) flags[1 + slot] = b;
  }
  float hv = (cnt_ex < KWIN) ? (float)hn : 0.f;
  hh[(size_t)b * ND + d] = (f16)hv;
}

// ---------------- fixup pass 1: exact GEMV for flagged rows (two-prod -> f64 accum) ----------------
__global__ __launch_bounds__(256) void fixup_gemv(const float* __restrict__ meanp, const float* __restrict__ varp,
                                                  const float* __restrict__ W1, const int* __restrict__ flags,
                                                  double* __restrict__ p64) {
  int nf = flags[0]; if (nf > MAXFIX) nf = MAXFIX;
  int slot = blockIdx.x >> 6;
  int kb = blockIdx.x & (FKB - 1);
  if (slot >= nf) return;
  int r = flags[1 + slot];
  int t = threadIdx.x;
  __shared__ float xs[512];
  int k0 = kb << 9;
  for (int i = t; i < 512; i += 256) {
    const float* xb = (i & 256) ? varp : meanp;
    xs[i] = xb[(((size_t)r * NF + kb) << 8) + (i & 255)];
  }
  __syncthreads();
  double accp0 = 0.0, accp1 = 0.0, acce0 = 0.0, acce1 = 0.0;
  const float* wcol = W1 + (size_t)k0 * ND + t;
#pragma unroll 8
  for (int i = 0; i < 512; i += 2) {
    float x0 = xs[i], w0 = wcol[(size_t)i * ND];
    float x1 = xs[i + 1], w1 = wcol[(size_t)(i + 1) * ND];
    float p0 = x0 * w0, p1 = x1 * w1;
    float e0 = fmaf(x0, w0, -p0), e1 = fmaf(x1, w1, -p1);
    accp0 += (double)p0;
    accp1 += (double)p1;
    acce0 += (double)e0;
    acce1 += (double)e1;
  }
  p64[((size_t)slot * FKB + kb) * ND + t] = (accp0 + accp1) + (acce0 + acce1);
}

// ---------------- fixup pass 2: f64 GELU + LN + exact kWTA for flagged rows ----------------
__global__ __launch_bounds__(256) void fixup_ln_kwta(const double* __restrict__ p64, const float* __restrict__ b1,
                                                     const float* __restrict__ gamma, const float* __restrict__ beta,
                                                     const int* __restrict__ flags,
                                                     f16* __restrict__ hh) {
  int nf = flags[0]; if (nf > MAXFIX) nf = MAXFIX;
  int slot = blockIdx.x;
  if (slot >= nf) return;
  int r = flags[1 + slot];
  int d = threadIdx.x;
  double s = 0.0;
#pragma unroll
  for (int kb = 0; kb < FKB; ++kb) s += p64[((size_t)slot * FKB + kb) * ND + d];
  s += (double)b1[d];
  double g = 0.5 * s * (1.0 + erf(s * 0.70710678118654752440));
  __shared__ double sredd[4];
  double mu = block_sum_f64(g, sredd) * (1.0 / 256.0);
  double dv = g - mu;
  double var = block_sum_f64(dv * dv, sredd) * (1.0 / 256.0);
  double hn = dv * (1.0 / sqrt(var + 1e-3)) * (double)gamma[d] + (double)beta[d];
  double a = fabs(hn);
  __shared__ double as_[256];
  as_[d] = a;
  __syncthreads();
  int cnt = 0;
  for (int j = 0; j < 256; ++j) {
    double aj = as_[j];
    cnt += ((aj > a) || (aj == a && j < d)) ? 1 : 0;
  }
  double hvd = (cnt < KWIN) ? hn : 0.0;
  hh[(size_t)r * ND + d] = (f16)(float)hvd;
}

// ---------------- GEMM2: plain f16 (hi x hi); output noise ~2e-3 << 0.02 threshold. 2-phase dbuf ----------------
__global__ __launch_bounds__(512, 4) void gemm2_kernel(const f16* __restrict__ hh,
                                                       const f16* __restrict__ w2h,
                                                       const float* __restrict__ b2, float* __restrict__ outp) {
  __shared__ alignas(16) f16 sAh[2][128 * 32];
  __shared__ alignas(16) f16 sBh[2][128 * 32];
  int t = threadIdx.x;
  int bm = (blockIdx.x & 7) << 7;
  int bn = (blockIdx.x >> 3) << 7;
  int wid = t >> 6, lane = t & 63, lr = lane & 15, lk = lane >> 4;
  int wr = wid >> 1, wc = wid & 1;
  f32x4 acc0[2][4] = {};
  int anr = t >> 2, aslot = t & 3;

  auto STAGE = [&](int sv, int buf) {
    int k0 = (sv & 7) << 5;
    size_t goa = (size_t)(bm + anr) * ND + k0 + (size_t)(swz4(anr, aslot) << 3);
    size_t gob = (size_t)(bn + anr) * ND + k0 + (size_t)(swz4(anr, aslot) << 3);
    gl2lds16(hh + goa, (char*)&sAh[buf][0] + (wid << 10));
    gl2lds16(w2h + gob, (char*)&sBh[buf][0] + (wid << 10));
  };

  STAGE(0, 0);
  __syncthreads();

  int cur = 0;
  for (int s = 0; s < 8; ++s) {
    int nxt = cur ^ 1;
    STAGE(s + 1, nxt);
    f16x8 ah[2], bh[4];
#pragma unroll
    for (int m = 0; m < 2; ++m) {
      int row = (wr << 5) + (m << 4) + lr;
      int byte = (row << 6) + (swz4(row, lk) << 4);
      ah[m] = *(const f16x8*)((const char*)&sAh[cur][0] + byte);
    }
#pragma unroll
    for (int n = 0; n < 4; ++n) {
      int col = (wc << 6) + (n << 4) + lr;
      int byte = (col << 6) + (swz4(col, lk) << 4);
      bh[n] = *(const f16x8*)((const char*)&sBh[cur][0] + byte);
    }
#pragma unroll
    for (int m = 0; m < 2; ++m)
#pragma unroll
      for (int n = 0; n < 4; ++n)
        acc0[m][n] = __builtin_amdgcn_mfma_f32_16x16x32_f16(ah[m], bh[n], acc0[m][n], 0, 0, 0);
    __syncthreads();
    cur = nxt;
  }
#pragma unroll
  for (int m = 0; m < 2; ++m)
#pragma unroll
    for (int n = 0; n < 4; ++n)
#pragma unroll
      for (int r = 0; r < 4; ++r) {
        int row = bm + (wr << 5) + (m << 4) + (lk << 2) + r;
        int col = bn + (wc << 6) + (n << 4) + lr;
        float val = acc0[m][n][r] * INV_WS + b2[col];
        float av = fabsf(val);
        float e = __expf(-2.0f * av);
        float rr = (1.0f - e) / (1.0f + e);
        outp[(size_t)row * OUTC + col] = copysignf(rr, val);
      }
}

extern "C" void kernel_launch(void* const* d_in, const int* in_sizes, int n_in,
                              void* d_out, int out_size, void* d_ws, size_t ws_size,
                              hipStream_t stream) {
  (void)in_sizes; (void)n_in; (void)out_size; (void)ws_size;
  const float* meanp = (const float*)d_in[0];
  const float* varp  = (const float*)d_in[1];
  const float* W1    = (const float*)d_in[2];
  const float* b1    = (const float*)d_in[3];
  const float* gamma = (const float*)d_in[4];
  const float* beta  = (const float*)d_in[5];
  const float* W2    = (const float*)d_in[6];
  const float* b2    = (const float*)d_in[7];
  float* outp = (float*)d_out;
  char* ws = (char*)d_ws;

  f16* w1h = (f16*)(ws);                              // 16 MiB: [256][32768]
  f16* w1l = (f16*)(ws + ((size_t)16 << 20));         // 16 MiB
  f16* w2h = (f16*)(ws + ((size_t)32 << 20));         // 4 MiB: [8192][256] (hi only)
  float* partial = (float*)(ws + ((size_t)40 << 20)); // 32 MiB: [32][1024][256]
  double* p64 = (double*)(ws + ((size_t)40 << 20));   // 2.1 MiB, aliases partial (consumed before use)
  f16* hh = (f16*)(ws + ((size_t)72 << 20));          // 512 KiB
  int* flags = (int*)(ws + ((size_t)73 << 20));       // nflag + rows[MAXFIX]

  transpose_split2<<<2560, 256, 0, stream>>>(W1, w1h, w1l, W2, w2h, flags);
  gemm1_kernel<<<512, 256, 0, stream>>>(meanp, varp, w1h, w1l, partial);
  reduce_ln_kwta<<<NB, 256, 0, stream>>>(partial, b1, gamma, beta, hh, flags);
  fixup_gemv<<<MAXFIX * FKB, 256, 0, stream>>>(meanp, varp, W1, flags, p64);
  fixup_ln_kwta<<<MAXFIX, 256, 0, stream>>>(p64, b1, gamma, beta, flags, hh);
  gemm2_kernel<<<512, 512, 0, stream>>>(hh, w2h, b2, outp);
}